// Round 3
// baseline (80.268 us; speedup 1.0000x reference)
//
#include <hip/hip_runtime.h>
#include <hip/hip_bf16.h>

typedef unsigned short ushort_t;
typedef __attribute__((ext_vector_type(8))) short short8;
typedef __attribute__((ext_vector_type(4))) float floatx4;
typedef __attribute__((ext_vector_type(4))) int intx4;

#define SIG_CH 584
#define KPAD   608      // 19 * 32
#define NKB    76       // KPAD / 8
#define NPROJ  128
#define ASTRIDE 616     // bf16 elems; 616*2 B row stride: 16B aligned, bank-uniform
#define TLEN   4096
#define NWIN   32768    // B*T

__device__ __forceinline__ ushort_t f2bf(float f) {
    unsigned int v; __builtin_memcpy(&v, &f, 4);
    v += 0x7fffu + ((v >> 16) & 1u);   // round-to-nearest-even
    return (ushort_t)(v >> 16);
}

// Pack W (584x128 fp32, row-major) into bf16 (kb, n, kk), K zero-padded to 608.
// Thread id -> (c, n) with n fastest: coalesced reads of w.
__global__ void pack_w_kernel(const float* __restrict__ w, ushort_t* __restrict__ wp) {
    int idx = blockIdx.x * 256 + threadIdx.x;
    if (idx >= KPAD * NPROJ) return;
    int n = idx & (NPROJ - 1);
    int c = idx >> 7;
    ushort_t v = 0;
    if (c < SIG_CH) v = f2bf(w[c * NPROJ + n]);
    int kb = c >> 3, kk = c & 7;
    wp[((size_t)kb * NPROJ + n) * 8 + kk] = v;
}

__launch_bounds__(256, 2)
__global__ void sig_gemm_kernel(const float* __restrict__ x,
                                const ushort_t* __restrict__ wp,
                                const float* __restrict__ bias,
                                float* __restrict__ out) {
    __shared__ float    s_dinc[70][8];        // increments for this block's 64 windows
    __shared__ ushort_t s_A[64][ASTRIDE];     // bf16 signature tile (GEMM A)

    const int tid  = threadIdx.x;
    const int blk  = blockIdx.x;              // 512 blocks
    const int g0   = blk * 64;                // first global window index
    const int b    = g0 >> 12;                // / 4096
    const int t0   = g0 & (TLEN - 1);
    const float* xb = x + (size_t)b * TLEN * 8;

    // ---- phase 0: increments into LDS (clamped indices -> zero increments) ----
    for (int idx = tid; idx < 70 * 8; idx += 256) {
        int s  = idx >> 3, k = idx & 7;
        int ta = t0 - 7 + s;
        int tb = ta + 1;
        ta = ta < 0 ? 0 : ta;
        tb = tb < 0 ? 0 : tb;
        s_dinc[s][k] = xb[tb * 8 + k] - xb[ta * 8 + k];
    }
    // zero A pad columns [584, 616)
    for (int idx = tid; idx < 64 * 32; idx += 256) {
        int r = idx >> 5, c = SIG_CH + (idx & 31);
        s_A[r][c] = 0;
    }
    __syncthreads();

    // ---- phase 1: signatures (1 wave = 16 windows; lane (i,j) owns s2[i][j], s3[i][j][:]) ----
    const int wv   = tid >> 6;     // wave 0..3
    const int lane = tid & 63;
    const int li   = lane >> 3;    // i
    const int lj   = lane & 7;     // j

    #pragma unroll 1
    for (int ww = 0; ww < 16; ++ww) {
        const int w = wv * 16 + ww;
        float h = 0.f, g = 0.f, s2 = 0.f;
        float s3[8] = {0.f, 0.f, 0.f, 0.f, 0.f, 0.f, 0.f, 0.f};
        #pragma unroll
        for (int st = 0; st < 7; ++st) {
            const floatx4 d0 = *(const floatx4*)(&s_dinc[w + st][0]);  // wave-uniform broadcast
            const floatx4 d1 = *(const floatx4*)(&s_dinc[w + st][4]);
            const float di = s_dinc[w + st][li];   // 8-addr broadcast, conflict-free
            const float dj = s_dinc[w + st][lj];
            // c3 = s2_old + 0.5*s1i_old*dj + di*dj/6 ; s2' = s2_old + s1i_old*dj + 0.5*di*dj
            const float c3 = fmaf(dj, fmaf(0.166666667f, di, 0.5f * h), s2);
            s2 = fmaf(dj, fmaf(0.5f, di, h), s2);
            s3[0] = fmaf(c3, d0[0], s3[0]);
            s3[1] = fmaf(c3, d0[1], s3[1]);
            s3[2] = fmaf(c3, d0[2], s3[2]);
            s3[3] = fmaf(c3, d0[3], s3[3]);
            s3[4] = fmaf(c3, d1[0], s3[4]);
            s3[5] = fmaf(c3, d1[1], s3[5]);
            s3[6] = fmaf(c3, d1[2], s3[6]);
            s3[7] = fmaf(c3, d1[3], s3[7]);
            h += di;
            g += dj;
        }
        // write sig row: [s1(8) | s2(64) | s3(512)] as bf16
        union { ushort_t u[8]; intx4 v; } pk;
        #pragma unroll
        for (int k = 0; k < 8; ++k) pk.u[k] = f2bf(s3[k]);
        *(intx4*)(&s_A[w][72 + lane * 8]) = pk.v;   // 16B aligned: row stride 1232B, off 144+16*lane
        s_A[w][8 + lane] = f2bf(s2);
        if (lane < 8) s_A[w][lane] = f2bf(g);       // lane<8 has i=0, j=lane -> s1[j]
    }
    __syncthreads();

    // ---- phase 2: GEMM 64x128 @ K=608, wave = 32-col n-slice over all 64 rows ----
    const int lrow  = lane & 15;   // A row within 16-tile / output col within fragment
    const int kgrp  = lane >> 4;   // k-group (k = kgrp*8 + j)
    const int ncol0 = wv * 32 + lrow;

    floatx4 acc[4][2];
    #pragma unroll
    for (int mt = 0; mt < 4; ++mt) {
        acc[mt][0] = floatx4{0.f, 0.f, 0.f, 0.f};
        acc[mt][1] = floatx4{0.f, 0.f, 0.f, 0.f};
    }

    for (int kc = 0; kc < 19; ++kc) {
        const int kb = kc * 4 + kgrp;
        const short8 b0 = *(const short8*)(wp + ((size_t)kb * NPROJ + ncol0) * 8);
        const short8 b1 = *(const short8*)(wp + ((size_t)kb * NPROJ + ncol0 + 16) * 8);
        #pragma unroll
        for (int mt = 0; mt < 4; ++mt) {
            const short8 af = *(const short8*)(&s_A[mt * 16 + lrow][kc * 32 + kgrp * 8]);
            acc[mt][0] = __builtin_amdgcn_mfma_f32_16x16x32_bf16(af, b0, acc[mt][0], 0, 0, 0);
            acc[mt][1] = __builtin_amdgcn_mfma_f32_16x16x32_bf16(af, b1, acc[mt][1], 0, 0, 0);
        }
    }

    const float bias0 = bias[ncol0];
    const float bias1 = bias[ncol0 + 16];
    #pragma unroll
    for (int mt = 0; mt < 4; ++mt) {
        #pragma unroll
        for (int r = 0; r < 4; ++r) {
            const int row = g0 + mt * 16 + kgrp * 4 + r;   // C/D: row = quad*4 + reg
            out[(size_t)row * NPROJ + ncol0]      = acc[mt][0][r] + bias0;
            out[(size_t)row * NPROJ + ncol0 + 16] = acc[mt][1][r] + bias1;
        }
    }
}

extern "C" void kernel_launch(void* const* d_in, const int* in_sizes, int n_in,
                              void* d_out, int out_size, void* d_ws, size_t ws_size,
                              hipStream_t stream) {
    const float* x  = (const float*)d_in[0];   // (8,4096,8) fp32
    const float* w  = (const float*)d_in[1];   // (584,128) fp32
    const float* bp = (const float*)d_in[2];   // (128,) fp32
    ushort_t* wp  = (ushort_t*)d_ws;           // 76*128*8*2 = 155,648 B of scratch
    float* out = (float*)d_out;                // (8,4096,128) fp32

    hipLaunchKernelGGL(pack_w_kernel, dim3((KPAD * NPROJ + 255) / 256), dim3(256), 0, stream,
                       w, wp);
    hipLaunchKernelGGL(sig_gemm_kernel, dim3(NWIN / 64), dim3(256), 0, stream,
                       x, wp, bp, out);
}

// Round 4
// 78.719 us; speedup vs baseline: 1.0197x; 1.0197x over previous
//
#include <hip/hip_runtime.h>
#include <hip/hip_bf16.h>

typedef unsigned short ushort_t;
typedef __attribute__((ext_vector_type(8))) short short8;
typedef __attribute__((ext_vector_type(4))) float floatx4;
typedef __attribute__((ext_vector_type(4))) int intx4;

#define SIG_CH 584
#define KPAD   608      // 19 * 32
#define NKB    76       // KPAD / 8
#define NPROJ  128
#define ASTRIDE 616     // bf16 elems; 616*2 B row stride: 16B aligned, bank-uniform
#define TLEN   4096
#define NWIN   32768    // B*T
#define DROWS  4103     // 8 zero-pad rows + 4095 increment rows

__device__ __forceinline__ ushort_t f2bf(float f) {
    unsigned int v; __builtin_memcpy(&v, &f, 4);
    v += 0x7fffu + ((v >> 16) & 1u);   // round-to-nearest-even
    return (ushort_t)(v >> 16);
}

// One prep kernel: (a) pack W (584x128 fp32) into bf16 (kb,n,kk) K-padded to 608;
// (b) write zero-padded fp32 increments dincP[b][8+ta][k] (rows 0..7 zero).
__global__ void pack_kernel(const float* __restrict__ w, const float* __restrict__ x,
                            ushort_t* __restrict__ wp, float* __restrict__ dincP) {
    int idx = blockIdx.x * 256 + threadIdx.x;
    if (idx < KPAD * NPROJ) {
        int n = idx & (NPROJ - 1);
        int c = idx >> 7;
        ushort_t v = 0;
        if (c < SIG_CH) v = f2bf(w[c * NPROJ + n]);
        wp[((size_t)(c >> 3) * NPROJ + n) * 8 + (c & 7)] = v;
        return;
    }
    int id2 = idx - KPAD * NPROJ;
    if (id2 >= 8 * DROWS * 8) return;
    int k  = id2 & 7;
    int rr = (id2 >> 3) % DROWS;
    int b  = (id2 >> 3) / DROWS;
    float v = 0.f;
    if (rr >= 8) {
        int ta = rr - 8;                       // 0..4094
        const float* xb = x + (size_t)b * TLEN * 8;
        v = xb[(ta + 1) * 8 + k] - xb[ta * 8 + k];
    }
    dincP[((size_t)b * DROWS + rr) * 8 + k] = v;
}

__launch_bounds__(256, 2)
__global__ void sig_gemm_kernel(const float* __restrict__ dincP,
                                const ushort_t* __restrict__ wp,
                                const float* __restrict__ bias,
                                float* __restrict__ out) {
    __shared__ float    s_dinc[70][8];        // increments for this block's 64 windows
    __shared__ ushort_t s_A[64][ASTRIDE];     // bf16 signature tile (GEMM A)

    const int tid  = threadIdx.x;
    const int blk  = blockIdx.x;              // 512 blocks
    const int g0   = blk * 64;                // first global window index
    const int b    = g0 >> 12;                // / 4096
    const int t0   = g0 & (TLEN - 1);
    const float* dincB = dincP + (size_t)b * DROWS * 8;

    // ---- phase 0: this block's increments into LDS (pre-padded, no clamp logic) ----
    for (int idx = tid; idx < 70 * 8; idx += 256) {
        int s = idx >> 3, k = idx & 7;
        s_dinc[s][k] = dincB[(size_t)(t0 + 1 + s) * 8 + k];   // row 8+(t0-7+s)
    }
    // zero A pad columns [584, 616)
    for (int idx = tid; idx < 64 * 32; idx += 256) {
        int r = idx >> 5, c = SIG_CH + (idx & 31);
        s_A[r][c] = 0;
    }
    __syncthreads();

    // ---- phase 1: signatures (1 wave = 16 windows; lane (i,j) owns s2[i][j], s3[i][j][:]) ----
    const int wv   = tid >> 6;     // wave 0..3
    const int lane = tid & 63;
    const int li   = lane >> 3;    // i
    const int lj   = lane & 7;     // j

    #pragma unroll 1
    for (int ww = 0; ww < 16; ++ww) {
        const int w = wv * 16 + ww;
        // wave-uniform base for this window's 7x8 increment block -> s_load path
        const int  woff = __builtin_amdgcn_readfirstlane((t0 + 1 + w) * 8);
        const float* dw = dincB + woff;       // dw[st*8 + k]

        float h = 0.f, g = 0.f, s2 = 0.f;
        float s3[8] = {0.f, 0.f, 0.f, 0.f, 0.f, 0.f, 0.f, 0.f};
        #pragma unroll
        for (int st = 0; st < 7; ++st) {
            const float di = s_dinc[w + st][li];   // 8-addr broadcast b32, conflict-free
            const float dj = s_dinc[w + st][lj];
            // c3 = s2_old + 0.5*s1i_old*dj + di*dj/6 ; s2' = s2_old + s1i_old*dj + 0.5*di*dj
            const float c3 = fmaf(dj, fmaf(0.166666667f, di, 0.5f * h), s2);
            s2 = fmaf(dj, fmaf(0.5f, di, h), s2);
            #pragma unroll
            for (int k = 0; k < 8; ++k)
                s3[k] = fmaf(c3, dw[st * 8 + k], s3[k]);   // SGPR operand per fma
            h += di;
            g += dj;
        }
        // write sig row: [s1(8) | s2(64) | s3(512)] as bf16
        union { ushort_t u[8]; intx4 v; } pk;
        #pragma unroll
        for (int k = 0; k < 8; ++k) pk.u[k] = f2bf(s3[k]);
        *(intx4*)(&s_A[w][72 + lane * 8]) = pk.v;   // 16B aligned: row stride 1232B, off 144+16*lane
        s_A[w][8 + lane] = f2bf(s2);
        if (lane < 8) s_A[w][lane] = f2bf(g);       // lane<8 has i=0, j=lane -> s1[j]
    }
    __syncthreads();

    // ---- phase 2: GEMM 64x128 @ K=608, wave = 32-col n-slice over all 64 rows ----
    const int lrow  = lane & 15;   // A row within 16-tile / output col within fragment
    const int kgrp  = lane >> 4;   // k-group (k = kgrp*8 + j)
    const int ncol0 = wv * 32 + lrow;

    floatx4 acc[4][2];
    #pragma unroll
    for (int mt = 0; mt < 4; ++mt) {
        acc[mt][0] = floatx4{0.f, 0.f, 0.f, 0.f};
        acc[mt][1] = floatx4{0.f, 0.f, 0.f, 0.f};
    }

    for (int kc = 0; kc < 19; ++kc) {
        const int kb = kc * 4 + kgrp;
        const short8 b0 = *(const short8*)(wp + ((size_t)kb * NPROJ + ncol0) * 8);
        const short8 b1 = *(const short8*)(wp + ((size_t)kb * NPROJ + ncol0 + 16) * 8);
        #pragma unroll
        for (int mt = 0; mt < 4; ++mt) {
            const short8 af = *(const short8*)(&s_A[mt * 16 + lrow][kc * 32 + kgrp * 8]);
            acc[mt][0] = __builtin_amdgcn_mfma_f32_16x16x32_bf16(af, b0, acc[mt][0], 0, 0, 0);
            acc[mt][1] = __builtin_amdgcn_mfma_f32_16x16x32_bf16(af, b1, acc[mt][1], 0, 0, 0);
        }
    }

    const float bias0 = bias[ncol0];
    const float bias1 = bias[ncol0 + 16];
    #pragma unroll
    for (int mt = 0; mt < 4; ++mt) {
        #pragma unroll
        for (int r = 0; r < 4; ++r) {
            const int row = g0 + mt * 16 + kgrp * 4 + r;   // C/D: row = quad*4 + reg
            out[(size_t)row * NPROJ + ncol0]      = acc[mt][0][r] + bias0;
            out[(size_t)row * NPROJ + ncol0 + 16] = acc[mt][1][r] + bias1;
        }
    }
}

extern "C" void kernel_launch(void* const* d_in, const int* in_sizes, int n_in,
                              void* d_out, int out_size, void* d_ws, size_t ws_size,
                              hipStream_t stream) {
    const float* x  = (const float*)d_in[0];   // (8,4096,8) fp32
    const float* w  = (const float*)d_in[1];   // (584,128) fp32
    const float* bp = (const float*)d_in[2];   // (128,) fp32
    ushort_t* wp    = (ushort_t*)d_ws;                         // 155,648 B
    float*    dincP = (float*)((char*)d_ws + 160 * 1024);      // 8*4103*8*4 = 1,050,368 B
    float* out = (float*)d_out;                // (8,4096,128) fp32

    const int prep_total = KPAD * NPROJ + 8 * DROWS * 8;
    hipLaunchKernelGGL(pack_kernel, dim3((prep_total + 255) / 256), dim3(256), 0, stream,
                       w, x, wp, dincP);
    hipLaunchKernelGGL(sig_gemm_kernel, dim3(NWIN / 64), dim3(256), 0, stream,
                       dincP, wp, bp, out);
}

// Round 5
// 75.228 us; speedup vs baseline: 1.0670x; 1.0464x over previous
//
#include <hip/hip_runtime.h>
#include <hip/hip_bf16.h>

typedef unsigned short ushort_t;
typedef __attribute__((ext_vector_type(8))) short short8;
typedef __attribute__((ext_vector_type(4))) float floatx4;
typedef __attribute__((ext_vector_type(4))) int intx4;

#define SIG_CH 584
#define KPAD   608      // 19 * 32
#define NKB    76       // KPAD / 8
#define NPROJ  128
#define ASTRIDE 616     // bf16 elems; 616*2 B row stride: 16B aligned, bank-uniform
#define TLEN   4096
#define NWIN   32768    // B*T
#define DROWS  4103     // 8 zero-pad rows + 4095 increment rows
#define WPB    32       // windows per block (32 -> 40.6 KB LDS -> 3 blocks/CU)

__device__ __forceinline__ ushort_t f2bf(float f) {
    unsigned int v; __builtin_memcpy(&v, &f, 4);
    v += 0x7fffu + ((v >> 16) & 1u);   // round-to-nearest-even
    return (ushort_t)(v >> 16);
}

// One prep kernel: (a) pack W (584x128 fp32) into bf16 (kb,n,kk) K-padded to 608;
// (b) write zero-padded fp32 increments dincP[b][8+ta][k] (rows 0..7 zero).
__global__ void pack_kernel(const float* __restrict__ w, const float* __restrict__ x,
                            ushort_t* __restrict__ wp, float* __restrict__ dincP) {
    int idx = blockIdx.x * 256 + threadIdx.x;
    if (idx < KPAD * NPROJ) {
        int n = idx & (NPROJ - 1);
        int c = idx >> 7;
        ushort_t v = 0;
        if (c < SIG_CH) v = f2bf(w[c * NPROJ + n]);
        wp[((size_t)(c >> 3) * NPROJ + n) * 8 + (c & 7)] = v;
        return;
    }
    int id2 = idx - KPAD * NPROJ;
    if (id2 >= 8 * DROWS * 8) return;
    int k  = id2 & 7;
    int rr = (id2 >> 3) % DROWS;
    int b  = (id2 >> 3) / DROWS;
    float v = 0.f;
    if (rr >= 8) {
        int ta = rr - 8;                       // 0..4094
        const float* xb = x + (size_t)b * TLEN * 8;
        v = xb[(ta + 1) * 8 + k] - xb[ta * 8 + k];
    }
    dincP[((size_t)b * DROWS + rr) * 8 + k] = v;
}

__launch_bounds__(256, 3)
__global__ void sig_gemm_kernel(const float* __restrict__ dincP,
                                const ushort_t* __restrict__ wp,
                                const float* __restrict__ bias,
                                float* __restrict__ out) {
    __shared__ float    s_dinc[WPB + 6][8];    // 38 rows: increments for 32 windows
    __shared__ ushort_t s_A[WPB][ASTRIDE];     // bf16 signature tile (GEMM A)

    const int tid  = threadIdx.x;
    const int blk  = blockIdx.x;               // 1024 blocks
    const int g0   = blk * WPB;                // first global window index
    const int b    = g0 >> 12;                 // / 4096
    const int t0   = g0 & (TLEN - 1);
    const float* dincB = dincP + (size_t)b * DROWS * 8;

    // ---- phase 0: this block's increments into LDS (pre-padded; float4, one pass) ----
    if (tid < (WPB + 6) * 2) {
        ((floatx4*)s_dinc)[tid] =
            *(const floatx4*)(dincB + (size_t)(t0 + 1) * 8 + tid * 4);
    }
    // zero A pad columns [584, 616)
    for (int idx = tid; idx < WPB * 32; idx += 256) {
        int r = idx >> 5, c = SIG_CH + (idx & 31);
        s_A[r][c] = 0;
    }
    __syncthreads();

    // ---- phase 1: signatures (1 wave = 8 windows; lane (i,j) owns s2[i][j], s3[i][j][:]) ----
    const int wv   = tid >> 6;     // wave 0..3
    const int lane = tid & 63;
    const int li   = lane >> 3;    // i
    const int lj   = lane & 7;     // j

    #pragma unroll 1
    for (int ww = 0; ww < 8; ++ww) {
        const int w = wv * 8 + ww;
        // wave-uniform base for this window's 7x8 increment block -> s_load path
        const int  woff = __builtin_amdgcn_readfirstlane((t0 + 1 + w) * 8);
        const float* dw = dincB + woff;        // dw[st*8 + k]

        float h = 0.f, g = 0.f, s2 = 0.f;
        float s3[8] = {0.f, 0.f, 0.f, 0.f, 0.f, 0.f, 0.f, 0.f};
        #pragma unroll
        for (int st = 0; st < 7; ++st) {
            const float di = s_dinc[w + st][li];   // 8-addr broadcast b32, conflict-free
            const float dj = s_dinc[w + st][lj];
            // c3 = s2_old + 0.5*s1i_old*dj + di*dj/6 ; s2' = s2_old + s1i_old*dj + 0.5*di*dj
            const float c3 = fmaf(dj, fmaf(0.166666667f, di, 0.5f * h), s2);
            s2 = fmaf(dj, fmaf(0.5f, di, h), s2);
            #pragma unroll
            for (int k = 0; k < 8; ++k)
                s3[k] = fmaf(c3, dw[st * 8 + k], s3[k]);   // SGPR operand per fma
            h += di;
            g += dj;
        }
        // write sig row: [s1(8) | s2(64) | s3(512)] as bf16
        union { ushort_t u[8]; intx4 v; } pk;
        #pragma unroll
        for (int k = 0; k < 8; ++k) pk.u[k] = f2bf(s3[k]);
        *(intx4*)(&s_A[w][72 + lane * 8]) = pk.v;   // 16B aligned writes
        s_A[w][8 + lane] = f2bf(s2);
        if (lane < 8) s_A[w][lane] = f2bf(g);       // lane<8 has i=0, j=lane -> s1[j]
    }
    __syncthreads();

    // ---- phase 2: GEMM 32x128 @ K=608, wave = 32-col n-slice over all 32 rows ----
    const int lrow  = lane & 15;   // A row within 16-tile / output col within fragment
    const int kgrp  = lane >> 4;   // k-group (k = kgrp*8 + j)
    const int ncol0 = wv * 32 + lrow;

    floatx4 acc[2][2];
    #pragma unroll
    for (int mt = 0; mt < 2; ++mt) {
        acc[mt][0] = floatx4{0.f, 0.f, 0.f, 0.f};
        acc[mt][1] = floatx4{0.f, 0.f, 0.f, 0.f};
    }

    for (int kc = 0; kc < 19; ++kc) {
        const int kb = kc * 4 + kgrp;
        const short8 b0 = *(const short8*)(wp + ((size_t)kb * NPROJ + ncol0) * 8);
        const short8 b1 = *(const short8*)(wp + ((size_t)kb * NPROJ + ncol0 + 16) * 8);
        #pragma unroll
        for (int mt = 0; mt < 2; ++mt) {
            const short8 af = *(const short8*)(&s_A[mt * 16 + lrow][kc * 32 + kgrp * 8]);
            acc[mt][0] = __builtin_amdgcn_mfma_f32_16x16x32_bf16(af, b0, acc[mt][0], 0, 0, 0);
            acc[mt][1] = __builtin_amdgcn_mfma_f32_16x16x32_bf16(af, b1, acc[mt][1], 0, 0, 0);
        }
    }

    const float bias0 = bias[ncol0];
    const float bias1 = bias[ncol0 + 16];
    #pragma unroll
    for (int mt = 0; mt < 2; ++mt) {
        #pragma unroll
        for (int r = 0; r < 4; ++r) {
            const int row = g0 + mt * 16 + kgrp * 4 + r;   // C/D: row = quad*4 + reg
            out[(size_t)row * NPROJ + ncol0]      = acc[mt][0][r] + bias0;
            out[(size_t)row * NPROJ + ncol0 + 16] = acc[mt][1][r] + bias1;
        }
    }
}

extern "C" void kernel_launch(void* const* d_in, const int* in_sizes, int n_in,
                              void* d_out, int out_size, void* d_ws, size_t ws_size,
                              hipStream_t stream) {
    const float* x  = (const float*)d_in[0];   // (8,4096,8) fp32
    const float* w  = (const float*)d_in[1];   // (584,128) fp32
    const float* bp = (const float*)d_in[2];   // (128,) fp32
    ushort_t* wp    = (ushort_t*)d_ws;                         // 155,648 B
    float*    dincP = (float*)((char*)d_ws + 160 * 1024);      // 8*4103*8*4 = 1,050,368 B
    float* out = (float*)d_out;                // (8,4096,128) fp32

    const int prep_total = KPAD * NPROJ + 8 * DROWS * 8;
    hipLaunchKernelGGL(pack_kernel, dim3((prep_total + 255) / 256), dim3(256), 0, stream,
                       w, x, wp, dincP);
    hipLaunchKernelGGL(sig_gemm_kernel, dim3(NWIN / WPB), dim3(256), 0, stream,
                       dincP, wp, bp, out);
}